// Round 3
// baseline (43.337 us; speedup 1.0000x reference)
//
#include <hip/hip_runtime.h>

#define BATCH 256
#define UNITS 64
#define IFEAT 256
#define OFEAT 256

typedef __attribute__((ext_vector_type(8))) short v8s;   // 8 bf16 (4 VGPRs)
typedef __attribute__((ext_vector_type(4))) float v4f;   // MFMA acc / global f32x4

// fp32 -> bf16 round-to-nearest-even (finite inputs)
static __device__ __forceinline__ unsigned short f2bf(float f) {
    unsigned int x = __float_as_uint(f);
    unsigned int r = x + 0x7fffu + ((x >> 16) & 1u);
    return (unsigned short)(r >> 16);
}

static __device__ __forceinline__ float sigmoid_f(float x) {
    return 1.0f / (1.0f + __expf(-x));
}
static __device__ __forceinline__ float tanh_f(float x) {
    float ax = fabsf(x);
    float e = __expf(-2.0f * ax);
    float t = (1.0f - e) / (1.0f + e);
    return copysignf(t, x);
}

// ---------------------------------------------------------------------------
// Kernel H: hvec[w][u][o] = sum_i hinit[u][i] * w_h{r,z,n}[u][i][o]
// 384 blocks x 512 threads (12 waves/CU) streaming 50.3 MB coalesced.
// ---------------------------------------------------------------------------
__global__ __launch_bounds__(512, 8) void gru_hvec(
        const float* __restrict__ whr,
        const float* __restrict__ whz,
        const float* __restrict__ whn,
        const float* __restrict__ hinit,
        float* __restrict__ hv) {
    __shared__ float red[512];
    const int bid  = blockIdx.x;
    const int half = bid & 1;
    const int u    = (bid >> 1) & 63;
    const int w    = bid >> 7;                     // 0..2
    const float* wh = (w == 0) ? whr : (w == 1) ? whz : whn;

    const int t = threadIdx.x;
    const int o = half * 128 + (t & 127);
    const int c = t >> 7;                          // i-quarter 0..3
    const float* hp = hinit + u * IFEAT;
    const float* wp = wh + (size_t)u * IFEAT * OFEAT + o;

    float acc = 0.0f;
    const int i0 = c * 64;
#pragma unroll 8
    for (int i = 0; i < 64; ++i) {
        acc += hp[i0 + i] * wp[(size_t)(i0 + i) * OFEAT];
    }
    red[t] = acc;
    __syncthreads();
    if (c == 0)
        hv[((size_t)w * UNITS + u) * OFEAT + o] =
            red[t] + red[t + 128] + red[t + 256] + red[t + 384];
}

// ---------------------------------------------------------------------------
// Kernel G: fused 3-way MFMA GEMM + GRU epilogue.
// BM=64, BN=32, BK=32, 256 threads = 4 waves (2m x 2n), wave tile 32x16.
// grid = 2048 blocks (64u x 4mb x 8nb), XCD-swizzled (a unit's 32 blocks on
// one XCD). ~6 blocks/CU resident (20KB LDS, ~80 VGPR) -> TLP hides latency.
// Frag-linear LDS, register-transpose for W, 1 barrier/K-step, dbuf.
// ---------------------------------------------------------------------------
__global__ __launch_bounds__(256, 6) void gru_gemm(
    const float* __restrict__ x,
    const float* __restrict__ wir,
    const float* __restrict__ wiz,
    const float* __restrict__ win,
    const float* __restrict__ hinit,
    const float* __restrict__ hv,
    float* __restrict__ out) {
    // frag-linear: As[buf][kg][row][j], Bs[buf][g][kg][col][j] (j = k&7)
    __shared__ unsigned short As[2][4][64][8];         // 8 KB
    __shared__ unsigned short Bs[2][3][4][32][8];      // 12 KB

    const int bid = blockIdx.x;
    // XCD swizzle: unit u fixed per XCD (bid&7); 32 blocks per unit.
    const int u   = (bid & 7) + 8 * (bid >> 8);
    const int rem = (bid >> 3) & 31;
    const int b0  = (rem >> 3) * 64;       // batch tile (4)
    const int o0  = (rem & 7) * 32;        // output-feature tile (8)

    const int t    = threadIdx.x;
    const int lane = t & 63;
    const int wave = t >> 6;
    const int wm   = wave >> 1;            // 0/1
    const int wn   = wave & 1;             // 0/1
    const int lg   = lane >> 4;            // k-quad 0..3
    const int lr   = lane & 15;

    // A staging: row = t&63, kg = t>>6  (coalesced dwordx4, b128 write)
    const int arow = t & 63;
    const int akg  = t >> 6;
    const int a_gbase = (b0 + arow) * (UNITS * IFEAT) + u * IFEAT + akg * 8;

    // B staging: 384 items (g,kg,col) over 256 threads; waves 0,1 take two.
    const int it0 = t;
    const int c0  = it0 & 31, kg0 = (it0 >> 5) & 3, g0 = it0 >> 7;  // g0 in {0,1}
    const float* wp0 = (g0 == 0) ? wir : wiz;
    const bool has1 = (t < 128);
    const int it1 = 256 + t;               // 256..383 -> gate 2
    const int c1  = it1 & 31, kg1 = (it1 >> 5) & 3;
    const int bg0 = u * (IFEAT * OFEAT) + (kg0 * 8) * OFEAT + o0 + c0;
    const int bg1 = u * (IFEAT * OFEAT) + (kg1 * 8) * OFEAT + o0 + c1;

    v4f ra0, ra1;
    float rb0[8], rb1[8];

    auto stage_load = [&](int kk) {
        const float* ap = x + a_gbase + kk * 32;
        ra0 = *(const v4f*)ap;
        ra1 = *(const v4f*)(ap + 4);
        const int off0 = bg0 + kk * 32 * OFEAT;
#pragma unroll
        for (int j = 0; j < 8; ++j) rb0[j] = wp0[off0 + j * OFEAT];
        if (has1) {
            const int off1 = bg1 + kk * 32 * OFEAT;
#pragma unroll
            for (int j = 0; j < 8; ++j) rb1[j] = win[off1 + j * OFEAT];
        }
    };

    auto stage_write = [&](int bb) {
        v8s av;
        av[0] = (short)f2bf(ra0[0]); av[1] = (short)f2bf(ra0[1]);
        av[2] = (short)f2bf(ra0[2]); av[3] = (short)f2bf(ra0[3]);
        av[4] = (short)f2bf(ra1[0]); av[5] = (short)f2bf(ra1[1]);
        av[6] = (short)f2bf(ra1[2]); av[7] = (short)f2bf(ra1[3]);
        *(v8s*)&As[bb][akg][arow][0] = av;
        v8s bv0;
#pragma unroll
        for (int j = 0; j < 8; ++j) bv0[j] = (short)f2bf(rb0[j]);
        *(v8s*)&Bs[bb][g0][kg0][c0][0] = bv0;
        if (has1) {
            v8s bv1;
#pragma unroll
            for (int j = 0; j < 8; ++j) bv1[j] = (short)f2bf(rb1[j]);
            *(v8s*)&Bs[bb][2][kg1][c1][0] = bv1;
        }
    };

    v4f acc[3][2];
#pragma unroll
    for (int g = 0; g < 3; ++g)
#pragma unroll
        for (int mi = 0; mi < 2; ++mi)
            acc[g][mi] = (v4f){0.f, 0.f, 0.f, 0.f};

    stage_load(0);
    stage_write(0);            // prologue: full latency exposed once
    stage_load(1);
    __syncthreads();

#pragma unroll 2
    for (int kk = 0; kk < 8; ++kk) {
        const int bb = kk & 1;
        if (kk < 7) stage_write(bb ^ 1);   // data for kk+1 into other buffer
        if (kk < 6) stage_load(kk + 2);    // refill regs; lands under MFMAs

        v8s a0 = *(const v8s*)&As[bb][lg][wm * 32 + lr][0];
        v8s a1 = *(const v8s*)&As[bb][lg][wm * 32 + 16 + lr][0];
#pragma unroll
        for (int g = 0; g < 3; ++g) {
            v8s b = *(const v8s*)&Bs[bb][g][lg][wn * 16 + lr][0];
            acc[g][0] = __builtin_amdgcn_mfma_f32_16x16x32_bf16(a0, b, acc[g][0], 0, 0, 0);
            acc[g][1] = __builtin_amdgcn_mfma_f32_16x16x32_bf16(a1, b, acc[g][1], 0, 0, 0);
        }
        if (kk < 7) __syncthreads();       // writes(bb^1) visible, reads(bb) done
    }

    // ---- epilogue: GRU combine ----
    // C layout: col = lane&15, row = (lane>>4)*4 + reg
    const int o = o0 + wn * 16 + lr;
    const float hrv = hv[(0 * UNITS + u) * OFEAT + o];
    const float hzv = hv[(1 * UNITS + u) * OFEAT + o];
    const float hnv = hv[(2 * UNITS + u) * OFEAT + o];
    const float h0v = hinit[u * OFEAT + o];
    const int rbase = b0 + wm * 32 + lg * 4;
#pragma unroll
    for (int mi = 0; mi < 2; ++mi) {
#pragma unroll
        for (int jj = 0; jj < 4; ++jj) {
            const int row = rbase + mi * 16 + jj;
            const float r = sigmoid_f(acc[0][mi][jj] + hrv);
            const float z = sigmoid_f(acc[1][mi][jj] + hzv);
            const float n = tanh_f(acc[2][mi][jj] + r * hnv);
            out[(row * UNITS + u) * OFEAT + o] = (1.0f - z) * n + z * h0v;
        }
    }
}

extern "C" void kernel_launch(void* const* d_in, const int* in_sizes, int n_in,
                              void* d_out, int out_size, void* d_ws, size_t ws_size,
                              hipStream_t stream) {
    const float* x     = (const float*)d_in[0];
    const float* w_ir  = (const float*)d_in[1];
    const float* w_iz  = (const float*)d_in[2];
    const float* w_in  = (const float*)d_in[3];
    const float* w_hr  = (const float*)d_in[4];
    const float* w_hz  = (const float*)d_in[5];
    const float* w_hn  = (const float*)d_in[6];
    const float* hinit = (const float*)d_in[7];
    float* out = (float*)d_out;
    float* hv  = (float*)d_ws;   // 3*64*256 floats

    gru_hvec<<<dim3(384), dim3(512), 0, stream>>>(w_hr, w_hz, w_hn, hinit, hv);
    gru_gemm<<<dim3(2048), dim3(256), 0, stream>>>(x, w_ir, w_iz, w_in, hinit, hv, out);
}

// Round 4
// 40.605 us; speedup vs baseline: 1.0673x; 1.0673x over previous
//
#include <hip/hip_runtime.h>

#define BATCH 256
#define UNITS 64
#define IFEAT 256
#define OFEAT 256

typedef __attribute__((ext_vector_type(8))) short v8s;   // 8 bf16 (4 VGPRs)
typedef __attribute__((ext_vector_type(4))) float v4f;   // MFMA acc / global f32x4

// fp32 -> bf16 round-to-nearest-even (finite inputs)
static __device__ __forceinline__ unsigned short f2bf(float f) {
    unsigned int x = __float_as_uint(f);
    unsigned int r = x + 0x7fffu + ((x >> 16) & 1u);
    return (unsigned short)(r >> 16);
}

static __device__ __forceinline__ float sigmoid_f(float x) {
    return 1.0f / (1.0f + __expf(-x));
}
static __device__ __forceinline__ float tanh_f(float x) {
    float ax = fabsf(x);
    float e = __expf(-2.0f * ax);
    float t = (1.0f - e) / (1.0f + e);
    return copysignf(t, x);
}

// ---------------------------------------------------------------------------
// Kernel H: hvec[w][u][o] = sum_i hinit[u][i] * w_h{r,z,n}[u][i][o]
// 384 blocks x 512 threads streaming 50.3 MB coalesced.
// ---------------------------------------------------------------------------
__global__ __launch_bounds__(512, 8) void gru_hvec(
        const float* __restrict__ whr,
        const float* __restrict__ whz,
        const float* __restrict__ whn,
        const float* __restrict__ hinit,
        float* __restrict__ hv) {
    __shared__ float red[512];
    const int bid  = blockIdx.x;
    const int half = bid & 1;
    const int u    = (bid >> 1) & 63;
    const int w    = bid >> 7;                     // 0..2
    const float* wh = (w == 0) ? whr : (w == 1) ? whz : whn;

    const int t = threadIdx.x;
    const int o = half * 128 + (t & 127);
    const int c = t >> 7;                          // i-quarter 0..3
    const float* hp = hinit + u * IFEAT;
    const float* wp = wh + (size_t)u * IFEAT * OFEAT + o;

    float acc = 0.0f;
    const int i0 = c * 64;
#pragma unroll 8
    for (int i = 0; i < 64; ++i) {
        acc += hp[i0 + i] * wp[(size_t)(i0 + i) * OFEAT];
    }
    red[t] = acc;
    __syncthreads();
    if (c == 0)
        hv[((size_t)w * UNITS + u) * OFEAT + o] =
            red[t] + red[t + 128] + red[t + 256] + red[t + 384];
}

// ---------------------------------------------------------------------------
// Kernel G: fused 3-way MFMA GEMM + GRU epilogue.
// BM=64, BN=128, BK=32, 512 threads = 8 waves (2m x 4n), wave tile 32x32.
// A-tile (x) pre-staged ONCE into 32KB LDS with coalesced row reads
// (rotated layout As[kq][(row+kq)&63][j], conflict-free write+read).
// K-loop stages only B (register-transpose, conflict-free), dbuf, 1 barrier.
// LDS 80KB -> exactly 2 blocks/CU; grid 512 = 2/CU exact (16 waves/CU).
// ---------------------------------------------------------------------------
__global__ __launch_bounds__(512, 4) void gru_gemm(
    const float* __restrict__ x,
    const float* __restrict__ wir,
    const float* __restrict__ wiz,
    const float* __restrict__ win,
    const float* __restrict__ hinit,
    const float* __restrict__ hv,
    float* __restrict__ out) {
    __shared__ unsigned short As[32][64][8];         // [kq][row'][j]  32 KB
    __shared__ unsigned short Bs[2][3][4][128][8];   // [buf][g][kg][col][j] 48 KB

    const int bid = blockIdx.x;
    // XCD swizzle: unit's 8 blocks all on XCD u>>3; W-slice L2-shared by mb's.
    const int u   = (bid & 7) * 8 + (bid >> 6);
    const int k6  = (bid >> 3) & 7;
    const int b0  = (k6 >> 1) * 64;        // batch tile 0..3
    const int o0  = (k6 & 1) * 128;        // out-feature tile 0..1

    const int t    = threadIdx.x;
    const int lane = t & 63;
    const int wave = t >> 6;
    const int wm   = wave >> 2;            // 0/1
    const int wn   = wave & 3;             // 0..3
    const int lg   = lane >> 4;            // k-quad within step
    const int lr   = lane & 15;

    // ---- B staging assignment: col = t&127, kg = t>>7 (coalesced dwords) ----
    const int bcol = t & 127;
    const int bkg  = t >> 7;               // 0..3
    const int b_gbase = u * (IFEAT * OFEAT) + bkg * 8 * OFEAT + o0 + bcol;

    float rb0[8], rb1[8], rb2[8];

    auto bload = [&](int kk) {
        const int off = b_gbase + kk * 32 * OFEAT;
#pragma unroll
        for (int j = 0; j < 8; ++j) rb0[j] = wir[off + j * OFEAT];
#pragma unroll
        for (int j = 0; j < 8; ++j) rb1[j] = wiz[off + j * OFEAT];
#pragma unroll
        for (int j = 0; j < 8; ++j) rb2[j] = win[off + j * OFEAT];
    };

    auto bwrite = [&](int bb) {
        v8s v0, v1, v2;
#pragma unroll
        for (int j = 0; j < 8; ++j) v0[j] = (short)f2bf(rb0[j]);
#pragma unroll
        for (int j = 0; j < 8; ++j) v1[j] = (short)f2bf(rb1[j]);
#pragma unroll
        for (int j = 0; j < 8; ++j) v2[j] = (short)f2bf(rb2[j]);
        *(v8s*)&Bs[bb][0][bkg][bcol][0] = v0;
        *(v8s*)&Bs[bb][1][bkg][bcol][0] = v1;
        *(v8s*)&Bs[bb][2][bkg][bcol][0] = v2;
    };

    v4f acc[3][2][2];
#pragma unroll
    for (int g = 0; g < 3; ++g)
#pragma unroll
        for (int mi = 0; mi < 2; ++mi)
#pragma unroll
            for (int ni = 0; ni < 2; ++ni)
                acc[g][mi][ni] = (v4f){0.f, 0.f, 0.f, 0.f};

    // ---- prologue: B(0) loads in flight while A-tile is pre-staged ----
    bload(0);
    {
        const int kq   = t & 31;           // k-quad 0..31 (full K)
        const int rsub = t >> 5;           // 0..15
#pragma unroll
        for (int c = 0; c < 4; ++c) {
            const int row = c * 16 + rsub;
            const float* ap = x + (b0 + row) * (UNITS * IFEAT) + u * IFEAT + kq * 8;
            v4f q0 = *(const v4f*)ap;
            v4f q1 = *(const v4f*)(ap + 4);
            v8s av;
            av[0] = (short)f2bf(q0[0]); av[1] = (short)f2bf(q0[1]);
            av[2] = (short)f2bf(q0[2]); av[3] = (short)f2bf(q0[3]);
            av[4] = (short)f2bf(q1[0]); av[5] = (short)f2bf(q1[1]);
            av[6] = (short)f2bf(q1[2]); av[7] = (short)f2bf(q1[3]);
            *(v8s*)&As[kq][(row + kq) & 63][0] = av;
        }
    }
    bwrite(0);
    bload(1);
    __syncthreads();

#pragma unroll
    for (int kk = 0; kk < 8; ++kk) {
        const int bb = kk & 1;
        if (kk < 7) bwrite(bb ^ 1);        // data for kk+1 into other buffer
        if (kk < 6) bload(kk + 2);         // refill regs; lands under MFMAs

        const int kq0 = kk * 4 + lg;
        v8s a0 = *(const v8s*)&As[kq0][((wm * 32 + lr) + kq0) & 63][0];
        v8s a1 = *(const v8s*)&As[kq0][((wm * 32 + 16 + lr) + kq0) & 63][0];
#pragma unroll
        for (int g = 0; g < 3; ++g) {
#pragma unroll
            for (int ni = 0; ni < 2; ++ni) {
                v8s b = *(const v8s*)&Bs[bb][g][lg][wn * 32 + ni * 16 + lr][0];
                acc[g][0][ni] = __builtin_amdgcn_mfma_f32_16x16x32_bf16(a0, b, acc[g][0][ni], 0, 0, 0);
                acc[g][1][ni] = __builtin_amdgcn_mfma_f32_16x16x32_bf16(a1, b, acc[g][1][ni], 0, 0, 0);
            }
        }
        if (kk < 7) __syncthreads();       // writes(bb^1) visible, reads(bb) done
    }

    // ---- epilogue: GRU combine ----
    // C layout: col = lane&15, row = (lane>>4)*4 + reg
    const int obase = o0 + wn * 32 + lr;
    float hrv[2], hzv[2], hnv[2], h0v[2];
#pragma unroll
    for (int ni = 0; ni < 2; ++ni) {
        const int o = obase + ni * 16;
        hrv[ni] = hv[(0 * UNITS + u) * OFEAT + o];
        hzv[ni] = hv[(1 * UNITS + u) * OFEAT + o];
        hnv[ni] = hv[(2 * UNITS + u) * OFEAT + o];
        h0v[ni] = hinit[u * OFEAT + o];
    }
    const int rbase = b0 + wm * 32 + lg * 4;
#pragma unroll
    for (int mi = 0; mi < 2; ++mi) {
#pragma unroll
        for (int ni = 0; ni < 2; ++ni) {
            const int o = obase + ni * 16;
#pragma unroll
            for (int jj = 0; jj < 4; ++jj) {
                const int row = rbase + mi * 16 + jj;
                const float r = sigmoid_f(acc[0][mi][ni][jj] + hrv[ni]);
                const float z = sigmoid_f(acc[1][mi][ni][jj] + hzv[ni]);
                const float n = tanh_f(acc[2][mi][ni][jj] + r * hnv[ni]);
                out[(row * UNITS + u) * OFEAT + o] = (1.0f - z) * n + z * h0v[ni];
            }
        }
    }
}

extern "C" void kernel_launch(void* const* d_in, const int* in_sizes, int n_in,
                              void* d_out, int out_size, void* d_ws, size_t ws_size,
                              hipStream_t stream) {
    const float* x     = (const float*)d_in[0];
    const float* w_ir  = (const float*)d_in[1];
    const float* w_iz  = (const float*)d_in[2];
    const float* w_in  = (const float*)d_in[3];
    const float* w_hr  = (const float*)d_in[4];
    const float* w_hz  = (const float*)d_in[5];
    const float* w_hn  = (const float*)d_in[6];
    const float* hinit = (const float*)d_in[7];
    float* out = (float*)d_out;
    float* hv  = (float*)d_ws;   // 3*64*256 floats

    gru_hvec<<<dim3(384), dim3(512), 0, stream>>>(w_hr, w_hz, w_hn, hinit, hv);
    gru_gemm<<<dim3(512), dim3(512), 0, stream>>>(x, w_ir, w_iz, w_in, hinit, hv, out);
}

// Round 5
// 37.253 us; speedup vs baseline: 1.1633x; 1.0900x over previous
//
#include <hip/hip_runtime.h>

#define BATCH 256
#define UNITS 64
#define IFEAT 256
#define OFEAT 256

typedef __attribute__((ext_vector_type(8))) short v8s;   // 8 bf16 (4 VGPRs)
typedef __attribute__((ext_vector_type(4))) float v4f;   // MFMA acc / global f32x4

// fp32 -> bf16 round-to-nearest-even (finite inputs)
static __device__ __forceinline__ unsigned short f2bf(float f) {
    unsigned int x = __float_as_uint(f);
    unsigned int r = x + 0x7fffu + ((x >> 16) & 1u);
    return (unsigned short)(r >> 16);
}

static __device__ __forceinline__ float sigmoid_f(float x) {
    return 1.0f / (1.0f + __expf(-x));
}
static __device__ __forceinline__ float tanh_f(float x) {
    float ax = fabsf(x);
    float e = __expf(-2.0f * ax);
    float t = (1.0f - e) / (1.0f + e);
    return copysignf(t, x);
}

// ---------------------------------------------------------------------------
// Kernel H: hvec[w][u][o] = sum_i hinit[u][i] * w_h{r,z,n}[u][i][o]
// 384 blocks x 512 threads streaming 50.3 MB coalesced (~8.5us, HBM-bound).
// ---------------------------------------------------------------------------
__global__ __launch_bounds__(512, 8) void gru_hvec(
        const float* __restrict__ whr,
        const float* __restrict__ whz,
        const float* __restrict__ whn,
        const float* __restrict__ hinit,
        float* __restrict__ hv) {
    __shared__ float red[512];
    const int bid  = blockIdx.x;
    const int half = bid & 1;
    const int u    = (bid >> 1) & 63;
    const int w    = bid >> 7;                     // 0..2
    const float* wh = (w == 0) ? whr : (w == 1) ? whz : whn;

    const int t = threadIdx.x;
    const int o = half * 128 + (t & 127);
    const int c = t >> 7;                          // i-quarter 0..3
    const float* hp = hinit + u * IFEAT;
    const float* wp = wh + (size_t)u * IFEAT * OFEAT + o;

    float acc = 0.0f;
    const int i0 = c * 64;
#pragma unroll 8
    for (int i = 0; i < 64; ++i) {
        acc += hp[i0 + i] * wp[(size_t)(i0 + i) * OFEAT];
    }
    red[t] = acc;
    __syncthreads();
    if (c == 0)
        hv[((size_t)w * UNITS + u) * OFEAT + o] =
            red[t] + red[t + 128] + red[t + 256] + red[t + 384];
}

// ---------------------------------------------------------------------------
// Kernel G: fused 3-way MFMA GEMM + GRU epilogue — ZERO-BARRIER main loop.
// BM=64, BN=32, full K=256 staged once: A 32KB (rotated frag layout) +
// B 48KB (frag-linear, register-transposed). ONE __syncthreads per block,
// then 8 fully-unrolled K-steps of pure ds_read+MFMA (no barriers).
// 80KB LDS -> 2 blocks/CU: one block stages while the other computes.
// grid = 2048 (64u x 4mb x 8nb), unit-major per XCD for L2 sharing.
// ---------------------------------------------------------------------------
__global__ __launch_bounds__(256, 2) void gru_gemm(
    const float* __restrict__ x,
    const float* __restrict__ wir,
    const float* __restrict__ wiz,
    const float* __restrict__ win,
    const float* __restrict__ hinit,
    const float* __restrict__ hv,
    float* __restrict__ out) {
    __shared__ unsigned short As[32][64][8];       // [kq][row'][j]   32 KB
    __shared__ unsigned short Bs[3][32][32][8];    // [g][kq][col][j] 48 KB

    const int bid = blockIdx.x;
    // XCD swizzle: xcd = bid&7 owns units [xcd*8, xcd*8+8); within-XCD order
    // is unit-major then b0-major then o0 -> sharing blocks co-resident.
    const int idx = bid >> 3;                  // 0..255 within XCD
    const int u   = (bid & 7) * 8 + (idx >> 5);
    const int rem = idx & 31;
    const int b0  = (rem >> 3) * 64;           // batch tile 0..3
    const int o0  = (rem & 7) * 32;            // out-feature tile 0..7

    const int t    = threadIdx.x;
    const int lane = t & 63;
    const int wave = t >> 6;                   // 4 waves: 2m x 2n
    const int wm   = wave >> 1;                // 0/1
    const int wn   = wave & 1;                 // 0/1
    const int lg   = lane >> 4;                // k-quad within step
    const int lr   = lane & 15;

    // ---- stage B: all K, 3 gates, register-transpose, frag-linear ----
    // 3072 (g,kq,col) chunks over 256 threads = 12 each; g,kq static per c.
#pragma unroll
    for (int c = 0; c < 12; ++c) {
        const int id  = c * 256 + t;
        const int col = id & 31;
        const int kq  = (id >> 5) & 31;
        const int g   = id >> 10;              // = c>>2, constant-folded
        const float* wp = (g == 0) ? wir : (g == 1) ? wiz : win;
        const int off = u * (IFEAT * OFEAT) + (kq * 8) * OFEAT + o0 + col;
        float rb[8];
#pragma unroll
        for (int j = 0; j < 8; ++j) rb[j] = wp[off + j * OFEAT];
        v8s bv;
#pragma unroll
        for (int j = 0; j < 8; ++j) bv[j] = (short)f2bf(rb[j]);
        *(v8s*)&Bs[g][kq][col][0] = bv;
    }

    // ---- stage A: 64 rows x 256 k, rotated layout (R4-proven) ----
    {
        const int kq   = t & 31;               // k-quad 0..31
        const int rsub = t >> 5;               // 0..7
#pragma unroll
        for (int c = 0; c < 8; ++c) {
            const int row = c * 8 + rsub;
            const float* ap = x + (b0 + row) * (UNITS * IFEAT) + u * IFEAT + kq * 8;
            v4f q0 = *(const v4f*)ap;
            v4f q1 = *(const v4f*)(ap + 4);
            v8s av;
            av[0] = (short)f2bf(q0[0]); av[1] = (short)f2bf(q0[1]);
            av[2] = (short)f2bf(q0[2]); av[3] = (short)f2bf(q0[3]);
            av[4] = (short)f2bf(q1[0]); av[5] = (short)f2bf(q1[1]);
            av[6] = (short)f2bf(q1[2]); av[7] = (short)f2bf(q1[3]);
            *(v8s*)&As[kq][(row + kq) & 63][0] = av;
        }
    }

    __syncthreads();   // the ONLY barrier

    // ---- barrier-free MFMA phase: 8 K-steps fully unrolled ----
    v4f acc[3][2];
#pragma unroll
    for (int g = 0; g < 3; ++g)
#pragma unroll
        for (int mi = 0; mi < 2; ++mi)
            acc[g][mi] = (v4f){0.f, 0.f, 0.f, 0.f};

#pragma unroll
    for (int kk = 0; kk < 8; ++kk) {
        const int kq0 = kk * 4 + lg;
        v8s a0 = *(const v8s*)&As[kq0][((wm * 32 + lr) + kq0) & 63][0];
        v8s a1 = *(const v8s*)&As[kq0][((wm * 32 + 16 + lr) + kq0) & 63][0];
#pragma unroll
        for (int g = 0; g < 3; ++g) {
            v8s b = *(const v8s*)&Bs[g][kq0][wn * 16 + lr][0];
            acc[g][0] = __builtin_amdgcn_mfma_f32_16x16x32_bf16(a0, b, acc[g][0], 0, 0, 0);
            acc[g][1] = __builtin_amdgcn_mfma_f32_16x16x32_bf16(a1, b, acc[g][1], 0, 0, 0);
        }
    }

    // ---- epilogue: GRU combine ----
    // C layout: col = lane&15, row = (lane>>4)*4 + reg
    const int o = o0 + wn * 16 + lr;
    const float hrv = hv[(0 * UNITS + u) * OFEAT + o];
    const float hzv = hv[(1 * UNITS + u) * OFEAT + o];
    const float hnv = hv[(2 * UNITS + u) * OFEAT + o];
    const float h0v = hinit[u * OFEAT + o];
    const int rbase = b0 + wm * 32 + lg * 4;
#pragma unroll
    for (int mi = 0; mi < 2; ++mi) {
#pragma unroll
        for (int jj = 0; jj < 4; ++jj) {
            const int row = rbase + mi * 16 + jj;
            const float r = sigmoid_f(acc[0][mi][jj] + hrv);
            const float z = sigmoid_f(acc[1][mi][jj] + hzv);
            const float n = tanh_f(acc[2][mi][jj] + r * hnv);
            out[(row * UNITS + u) * OFEAT + o] = (1.0f - z) * n + z * h0v;
        }
    }
}

extern "C" void kernel_launch(void* const* d_in, const int* in_sizes, int n_in,
                              void* d_out, int out_size, void* d_ws, size_t ws_size,
                              hipStream_t stream) {
    const float* x     = (const float*)d_in[0];
    const float* w_ir  = (const float*)d_in[1];
    const float* w_iz  = (const float*)d_in[2];
    const float* w_in  = (const float*)d_in[3];
    const float* w_hr  = (const float*)d_in[4];
    const float* w_hz  = (const float*)d_in[5];
    const float* w_hn  = (const float*)d_in[6];
    const float* hinit = (const float*)d_in[7];
    float* out = (float*)d_out;
    float* hv  = (float*)d_ws;   // 3*64*256 floats

    gru_hvec<<<dim3(384), dim3(512), 0, stream>>>(w_hr, w_hz, w_hn, hinit, hv);
    gru_gemm<<<dim3(2048), dim3(256), 0, stream>>>(x, w_ir, w_iz, w_in, hinit, hv, out);
}